// Round 1
// baseline (392.599 us; speedup 1.0000x reference)
//
#include <hip/hip_runtime.h>

// ---- problem constants ----
#define B_DIM 8
#define C_DIM 256
#define I_DIM 128
#define N_DIM 4096
#define R_DIM 64

typedef unsigned short u16;
typedef __attribute__((ext_vector_type(8))) __bf16 bf16x8;
typedef __attribute__((ext_vector_type(4))) float f32x4;

__device__ __forceinline__ u16 f2bf(float f) {
    union { float f; unsigned u; } v; v.f = f;
    unsigned r = v.u + 0x7FFFu + ((v.u >> 16) & 1u);
    return (u16)(r >> 16);
}

// ---- workspace layout (bytes) ----
// bn_sum[256]f32 @0, bn_sumsq[256]f32 @1024, pooled[2048]f32 @2048,
// chw[2048]f32 @10240, W3 bf16[3*128*256] @18432, OW bf16[256*128] @215040,
// theta bf16[B,N,I] @280576, phiT bf16[B,N,I] @+8MB, gT bf16[B,I,N] @+16MB,
// ao bf16[B,N,I] @+24MB, out2 f32[B,C,N] @+32MB  -> total ~64.3 MB
static constexpr size_t OFF_BNSUM = 0;
static constexpr size_t OFF_BNSQ  = 1024;
static constexpr size_t OFF_POOL  = 2048;
static constexpr size_t OFF_CHW   = 10240;
static constexpr size_t OFF_W3    = 18432;
static constexpr size_t OFF_OWB   = 215040;
static constexpr size_t OFF_THETA = 280576;
static constexpr size_t OFF_PHIT  = OFF_THETA + 8388608;
static constexpr size_t OFF_GT    = OFF_PHIT  + 8388608;
static constexpr size_t OFF_AO    = OFF_GT    + 8388608;
static constexpr size_t OFF_OUT2  = OFF_AO    + 8388608;

// ---- 1: weight convert + zero BN stats ----
__global__ void prep_kernel(const float* __restrict__ tw, const float* __restrict__ pw,
                            const float* __restrict__ gw, const float* __restrict__ ow,
                            u16* __restrict__ w3, u16* __restrict__ owb,
                            float* __restrict__ bnzero) {
    int idx = blockIdx.x * 256 + threadIdx.x;
    if (idx < 512) bnzero[idx] = 0.f;
    if (idx < 3 * 32768) {
        const float* src = idx < 32768 ? tw : (idx < 65536 ? pw : gw);
        w3[idx] = f2bf(src[idx & 32767]);
    }
    if (idx < 32768) owb[idx] = f2bf(ow[idx]);
}

// ---- 2: SE pooling: pooled[b,c] = mean_n x[b,c,n] ----
__global__ void pool_kernel(const float* __restrict__ x, float* __restrict__ pooled) {
    int bc = blockIdx.x;  // 0..2047
    const float4* row = (const float4*)(x + (size_t)bc * N_DIM);
    int t = threadIdx.x;
    float s = 0.f;
    for (int it = 0; it < 4; ++it) {
        float4 v = row[t + it * 256];
        s += v.x + v.y + v.z + v.w;
    }
    for (int d = 32; d; d >>= 1) s += __shfl_down(s, d);
    __shared__ float ls[4];
    if ((t & 63) == 0) ls[t >> 6] = s;
    __syncthreads();
    if (t == 0) pooled[bc] = (ls[0] + ls[1] + ls[2] + ls[3]) * (1.f / N_DIM);
}

// ---- 3: SE MLP: chw[b,c] = sigmoid(fc2(relu(fc1(pooled)))) ----
__global__ void se_kernel(const float* __restrict__ pooled,
                          const float* __restrict__ fc1w, const float* __restrict__ fc1b,
                          const float* __restrict__ fc2w, const float* __restrict__ fc2b,
                          float* __restrict__ chw) {
    int b = blockIdx.x, t = threadIdx.x;
    __shared__ float sp[C_DIM], sh[R_DIM];
    sp[t] = pooled[b * C_DIM + t];
    __syncthreads();
    if (t < R_DIM) {
        float a = fc1b[t];
        for (int c = 0; c < C_DIM; ++c) a += sp[c] * fc1w[t * C_DIM + c];
        sh[t] = a > 0.f ? a : 0.f;
    }
    __syncthreads();
    float a = fc2b[t];
    for (int j = 0; j < R_DIM; ++j) a += sh[j] * fc2w[t * R_DIM + j];
    chw[b * C_DIM + t] = 1.f / (1.f + __builtin_amdgcn_exp2f(-a * 1.44269504089f));
}

// ---- 4: QKV projection: out[n,i] = sum_c W[i,c] * x[b,c,n] ----
// z=0 -> theta [B,N,I], z=1 -> phiT [B,N,I], z=2 -> gT [B,I,N]
__global__ __launch_bounds__(256) void qkv_kernel(const float* __restrict__ x,
                                                  const u16* __restrict__ w3,
                                                  u16* __restrict__ theta,
                                                  u16* __restrict__ phiT,
                                                  u16* __restrict__ gT) {
    const int nt = blockIdx.x;  // 64 tiles of 64 pixels
    const int b  = blockIdx.y;
    const int z  = blockIdx.z;
    const int n0 = nt * 64;
    const int t = threadIdx.x;
    const int lane = t & 63, w = t >> 6;
    const int col = lane & 15, quad = lane >> 4;

    __shared__ u16 As[64][264];  // [pixel][c], +8 pad (row stride 528B, 16B-aligned)

    {   // stage x[b, 0:256, n0:n0+64] -> As[n][c] (bf16, transposed)
        const float* xb = x + ((size_t)b * C_DIM) * N_DIM + n0;
        int cq = t >> 4;
        int nq = (t & 15) * 4;
        for (int it = 0; it < 16; ++it) {
            int c = cq + it * 16;
            float4 v = *(const float4*)(xb + (size_t)c * N_DIM + nq);
            As[nq + 0][c] = f2bf(v.x);
            As[nq + 1][c] = f2bf(v.y);
            As[nq + 2][c] = f2bf(v.z);
            As[nq + 3][c] = f2bf(v.w);
        }
    }
    __syncthreads();

    const u16* wz = w3 + (size_t)z * (I_DIM * C_DIM);
    f32x4 acc[8];
    for (int f = 0; f < 8; ++f) acc[f] = f32x4{0.f, 0.f, 0.f, 0.f};

    for (int kc = 0; kc < 8; ++kc) {
        bf16x8 a = *(const bf16x8*)&As[w * 16 + col][kc * 32 + quad * 8];
        for (int f = 0; f < 8; ++f) {
            bf16x8 bfr = *(const bf16x8*)(wz + (size_t)(f * 16 + col) * C_DIM + kc * 32 + quad * 8);
            acc[f] = __builtin_amdgcn_mfma_f32_16x16x32_bf16(a, bfr, acc[f], 0, 0, 0);
        }
    }
    // C/D layout: col = lane&15 (i), row = quad*4+reg (pixel)
    if (z < 2) {
        u16* dst = (z == 0) ? theta : phiT;
        for (int f = 0; f < 8; ++f)
            for (int r = 0; r < 4; ++r) {
                int n = n0 + w * 16 + quad * 4 + r;
                dst[((size_t)b * N_DIM + n) * I_DIM + f * 16 + col] = f2bf(acc[f][r]);
            }
    } else {
        for (int f = 0; f < 8; ++f)
            for (int r = 0; r < 4; ++r) {
                int n = n0 + w * 16 + quad * 4 + r;
                gT[((size_t)b * I_DIM + f * 16 + col) * N_DIM + n] = f2bf(acc[f][r]);
            }
    }
}

// ---- 5: flash attention: ao[b,n,i] = softmax_m(theta.phi / sqrt(I)) @ g ----
__global__ __launch_bounds__(256) void attn_kernel(const u16* __restrict__ theta,
                                                   const u16* __restrict__ phiT,
                                                   const u16* __restrict__ gT,
                                                   u16* __restrict__ ao) {
    const int qt = blockIdx.x;  // 64 q-tiles of 64
    const int b  = blockIdx.y;
    const int t = threadIdx.x;
    const int lane = t & 63, w = t >> 6;
    const int col = lane & 15, quad = lane >> 4;

    __shared__ u16 Ks[64][136];   // K-chunk [m][i], pad 8 (272B stride)
    __shared__ u16 Vs[128][72];   // V^T chunk [i][m], pad 8 (144B stride)
    __shared__ u16 Ps[4][16][72]; // per-wave P [q][m], pad 8

    // Q A-frags for this wave's 16 rows, K=128 in 4 chunks
    bf16x8 qf[4];
    {
        const u16* qp = theta + ((size_t)b * N_DIM + qt * 64 + w * 16 + col) * I_DIM + quad * 8;
        for (int kc = 0; kc < 4; ++kc) qf[kc] = *(const bf16x8*)(qp + kc * 32);
    }

    const float scale2 = 1.44269504089f / sqrtf(128.f);  // log2(e)/sqrt(I)
    float mrun[4], lrun[4];
    f32x4 oacc[8];
    for (int r = 0; r < 4; ++r) { mrun[r] = -1e30f; lrun[r] = 0.f; }
    for (int f = 0; f < 8; ++f) oacc[f] = f32x4{0.f, 0.f, 0.f, 0.f};

    const u16* kbase = phiT + (size_t)b * N_DIM * I_DIM;
    const u16* vbase = gT + (size_t)b * I_DIM * N_DIM;

    for (int mc = 0; mc < 64; ++mc) {
        const int m0 = mc * 64;
        __syncthreads();  // protect K/V from overwrite while prev iter reads
        for (int it = 0; it < 4; ++it) {  // stage K: 64 rows x 128 halfs
            int id = t + it * 256;
            int r = id >> 4, c8 = (id & 15) * 8;
            *(bf16x8*)&Ks[r][c8] = *(const bf16x8*)(kbase + (size_t)(m0 + r) * I_DIM + c8);
        }
        for (int it = 0; it < 4; ++it) {  // stage V^T: 128 rows x 64 halfs
            int id = t + it * 256;
            int i = id >> 3, c8 = (id & 7) * 8;
            *(bf16x8*)&Vs[i][c8] = *(const bf16x8*)(vbase + (size_t)i * N_DIM + m0 + c8);
        }
        __syncthreads();

        // S[16q x 64m] = Q K^T (in log2 domain)
        f32x4 S[4];
        for (int ms = 0; ms < 4; ++ms) {
            f32x4 a = f32x4{0.f, 0.f, 0.f, 0.f};
            for (int kc = 0; kc < 4; ++kc) {
                bf16x8 kf = *(const bf16x8*)&Ks[ms * 16 + col][kc * 32 + quad * 8];
                a = __builtin_amdgcn_mfma_f32_16x16x32_bf16(qf[kc], kf, a, 0, 0, 0);
            }
            S[ms] = a * scale2;
        }

        // online softmax, rows quad*4+r live on the 16 lanes sharing `quad`
        for (int r = 0; r < 4; ++r) {
            float cm = fmaxf(fmaxf(S[0][r], S[1][r]), fmaxf(S[2][r], S[3][r]));
            for (int d = 1; d < 16; d <<= 1) cm = fmaxf(cm, __shfl_xor(cm, d));
            float mnew = fmaxf(mrun[r], cm);
            float alpha = __builtin_amdgcn_exp2f(mrun[r] - mnew);
            mrun[r] = mnew;
            float rs = 0.f;
            for (int ms = 0; ms < 4; ++ms) {
                float p = __builtin_amdgcn_exp2f(S[ms][r] - mnew);
                rs += p;
                Ps[w][quad * 4 + r][ms * 16 + col] = f2bf(p);
            }
            for (int d = 1; d < 16; d <<= 1) rs += __shfl_xor(rs, d);
            lrun[r] = lrun[r] * alpha + rs;
            for (int f = 0; f < 8; ++f) oacc[f][r] *= alpha;
        }
        __syncthreads();  // P LDS write -> read ordering

        // O += P V   (P in A-layout via LDS round-trip, V^T gives B-layout)
        for (int f = 0; f < 8; ++f)
            for (int ks = 0; ks < 2; ++ks) {
                bf16x8 pf = *(const bf16x8*)&Ps[w][col][ks * 32 + quad * 8];
                bf16x8 vf = *(const bf16x8*)&Vs[f * 16 + col][ks * 32 + quad * 8];
                oacc[f] = __builtin_amdgcn_mfma_f32_16x16x32_bf16(pf, vf, oacc[f], 0, 0, 0);
            }
    }

    for (int r = 0; r < 4; ++r) {
        float linv = 1.f / lrun[r];
        int n = qt * 64 + w * 16 + quad * 4 + r;
        for (int f = 0; f < 8; ++f)
            ao[((size_t)b * N_DIM + n) * I_DIM + f * 16 + col] = f2bf(oacc[f][r] * linv);
    }
}

// ---- 6: out projection + BN stats: out2[b,c,n] = sum_i ow[c,i]*ao[b,n,i] ----
__global__ __launch_bounds__(256) void oproj_kernel(const u16* __restrict__ ao,
                                                    const u16* __restrict__ owb,
                                                    float* __restrict__ out2,
                                                    float* __restrict__ bnsum,
                                                    float* __restrict__ bnsumsq) {
    const int nt = blockIdx.x, b = blockIdx.y;
    const int t = threadIdx.x, lane = t & 63, w = t >> 6;
    const int col = lane & 15, quad = lane >> 4;
    const int n0 = nt * 64;

    __shared__ float lsum[C_DIM], lsq[C_DIM];
    lsum[t] = 0.f; lsq[t] = 0.f;
    __syncthreads();

    bf16x8 af[4];
    const u16* ap = ao + ((size_t)b * N_DIM + n0 + w * 16 + col) * I_DIM + quad * 8;
    for (int kc = 0; kc < 4; ++kc) af[kc] = *(const bf16x8*)(ap + kc * 32);

    for (int f = 0; f < 16; ++f) {
        f32x4 acc = f32x4{0.f, 0.f, 0.f, 0.f};
        for (int kc = 0; kc < 4; ++kc) {
            bf16x8 bfr = *(const bf16x8*)(owb + (size_t)(f * 16 + col) * I_DIM + kc * 32 + quad * 8);
            acc = __builtin_amdgcn_mfma_f32_16x16x32_bf16(af[kc], bfr, acc, 0, 0, 0);
        }
        int c = f * 16 + col;
        float s1 = 0.f, s2 = 0.f;
        for (int r = 0; r < 4; ++r) {
            int n = n0 + w * 16 + quad * 4 + r;
            out2[((size_t)b * C_DIM + c) * N_DIM + n] = acc[r];
            s1 += acc[r]; s2 += acc[r] * acc[r];
        }
        s1 += __shfl_xor(s1, 16); s2 += __shfl_xor(s2, 16);
        s1 += __shfl_xor(s1, 32); s2 += __shfl_xor(s2, 32);
        if (quad == 0) { atomicAdd(&lsum[c], s1); atomicAdd(&lsq[c], s2); }
    }
    __syncthreads();
    atomicAdd(&bnsum[t], lsum[t]);
    atomicAdd(&bnsumsq[t], lsq[t]);
}

// ---- 7: BN normalize + SE scale + residual ----
__global__ void final_kernel(const float* __restrict__ x, const float* __restrict__ out2,
                             const float* __restrict__ bnsum, const float* __restrict__ bnsumsq,
                             const float* __restrict__ gamma, const float* __restrict__ beta,
                             const float* __restrict__ chw, float* __restrict__ out) {
    int idx = blockIdx.x * 256 + threadIdx.x;  // float4 index
    int e = idx * 4;
    int b = e >> 20;           // / (C*N)
    int c = (e >> 12) & 255;   // / N % C
    float mean = bnsum[c] * (1.f / 32768.f);
    float var  = bnsumsq[c] * (1.f / 32768.f) - mean * mean;
    float sc = gamma[c] * rsqrtf(var + 1e-5f);
    float sh = beta[c] - mean * sc;
    float cw = chw[b * C_DIM + c];
    float4 o  = ((const float4*)out2)[idx];
    float4 xv = ((const float4*)x)[idx];
    float4 res;
    res.x = xv.x + (o.x * sc + sh) * cw;
    res.y = xv.y + (o.y * sc + sh) * cw;
    res.z = xv.z + (o.z * sc + sh) * cw;
    res.w = xv.w + (o.w * sc + sh) * cw;
    ((float4*)out)[idx] = res;
}

extern "C" void kernel_launch(void* const* d_in, const int* in_sizes, int n_in,
                              void* d_out, int out_size, void* d_ws, size_t ws_size,
                              hipStream_t stream) {
    const float* x   = (const float*)d_in[0];
    const float* tw  = (const float*)d_in[1];
    const float* pw  = (const float*)d_in[2];
    const float* gw  = (const float*)d_in[3];
    const float* ow  = (const float*)d_in[4];
    const float* gam = (const float*)d_in[5];
    const float* bet = (const float*)d_in[6];
    const float* f1w = (const float*)d_in[7];
    const float* f1b = (const float*)d_in[8];
    const float* f2w = (const float*)d_in[9];
    const float* f2b = (const float*)d_in[10];
    float* out = (float*)d_out;

    char* ws = (char*)d_ws;
    float* bnsum   = (float*)(ws + OFF_BNSUM);
    float* bnsumsq = (float*)(ws + OFF_BNSQ);
    float* pooled  = (float*)(ws + OFF_POOL);
    float* chw     = (float*)(ws + OFF_CHW);
    u16*   w3      = (u16*)(ws + OFF_W3);
    u16*   owb     = (u16*)(ws + OFF_OWB);
    u16*   theta   = (u16*)(ws + OFF_THETA);
    u16*   phiT    = (u16*)(ws + OFF_PHIT);
    u16*   gT      = (u16*)(ws + OFF_GT);
    u16*   ao      = (u16*)(ws + OFF_AO);
    float* out2    = (float*)(ws + OFF_OUT2);

    prep_kernel<<<384, 256, 0, stream>>>(tw, pw, gw, ow, w3, owb, bnsum);
    pool_kernel<<<B_DIM * C_DIM, 256, 0, stream>>>(x, pooled);
    se_kernel<<<B_DIM, 256, 0, stream>>>(pooled, f1w, f1b, f2w, f2b, chw);
    qkv_kernel<<<dim3(64, B_DIM, 3), 256, 0, stream>>>(x, w3, theta, phiT, gT);
    attn_kernel<<<dim3(64, B_DIM), 256, 0, stream>>>(theta, phiT, gT, ao);
    oproj_kernel<<<dim3(64, B_DIM), 256, 0, stream>>>(ao, owb, out2, bnsum, bnsumsq);
    final_kernel<<<8192, 256, 0, stream>>>(x, out2, bnsum, bnsumsq, gam, bet, chw, out);
}

// Round 2
// 337.121 us; speedup vs baseline: 1.1646x; 1.1646x over previous
//
#include <hip/hip_runtime.h>

#define B_DIM 8
#define C_DIM 256
#define I_DIM 128
#define N_DIM 4096
#define R_DIM 64

typedef unsigned short u16;
typedef __attribute__((ext_vector_type(8))) __bf16 bf16x8;
typedef __attribute__((ext_vector_type(4))) float f32x4;

__device__ __forceinline__ u16 f2bf(float f) {
    union { float f; unsigned u; } v; v.f = f;
    unsigned r = v.u + 0x7FFFu + ((v.u >> 16) & 1u);
    return (u16)(r >> 16);
}
__device__ __forceinline__ float bf2f(u16 v) {
    union { unsigned u; float f; } x; x.u = (unsigned)v << 16; return x.f;
}
// async global->LDS, 16B per lane; LDS dest = wave-uniform base + lane*16
__device__ __forceinline__ void async16(const u16* g, u16* l) {
    __builtin_amdgcn_global_load_lds((const __attribute__((address_space(1))) void*)g,
                                     (__attribute__((address_space(3))) void*)l, 16, 0, 0);
}

// log2(e)/sqrt(128), folded into theta at projection time
#define TH_SCALE 0.1275204890136f

// ---- workspace layout (bytes) ----
static constexpr size_t OFF_BNSUM = 0;
static constexpr size_t OFF_BNSQ  = 1024;
static constexpr size_t OFF_POOL  = 2048;
static constexpr size_t OFF_CHW   = 10240;
static constexpr size_t OFF_W3    = 18432;        // 3*128*256 bf16
static constexpr size_t OFF_OWB   = 215040;       // 256*128 bf16
static constexpr size_t OFF_XBT   = 280576;       // [B,N,C] bf16 = 16 MB
static constexpr size_t OFF_THETA = OFF_XBT + 16777216;   // [B,N,I] bf16 (pre-scaled)
static constexpr size_t OFF_PHIT  = OFF_THETA + 8388608;  // [B,N,I] bf16
static constexpr size_t OFF_GT    = OFF_PHIT  + 8388608;  // [B,I,N] bf16
static constexpr size_t OFF_AO    = OFF_GT    + 8388608;  // [B,N,I] bf16
static constexpr size_t OFF_OUT2  = OFF_AO    + 8388608;  // [B,C,N] bf16 = 16 MB

// ---- 1: weight convert + zero accumulators ----
__global__ void prep_kernel(const float* __restrict__ tw, const float* __restrict__ pw,
                            const float* __restrict__ gw, const float* __restrict__ ow,
                            u16* __restrict__ w3, u16* __restrict__ owb,
                            float* __restrict__ bnzero, float* __restrict__ pooled) {
    int idx = blockIdx.x * 256 + threadIdx.x;
    if (idx < 512) bnzero[idx] = 0.f;
    if (idx < 2048) pooled[idx] = 0.f;
    if (idx < 3 * 32768) {
        const float* src = idx < 32768 ? tw : (idx < 65536 ? pw : gw);
        w3[idx] = f2bf(src[idx & 32767]);
    }
    if (idx < 32768) owb[idx] = f2bf(ow[idx]);
}

// ---- 2: x -> bf16 transposed [b][n][c], fused SE pooling ----
__global__ __launch_bounds__(256) void xt_kernel(const float* __restrict__ x,
                                                 u16* __restrict__ xbfT,
                                                 float* __restrict__ pooled) {
    const int c0 = blockIdx.x * 64, n0 = blockIdx.y * 64, b = blockIdx.z;
    const int t = threadIdx.x;
    const int cr = t >> 4, nq = (t & 15) * 4;
    #pragma unroll
    for (int it = 0; it < 4; ++it) {
        int c = c0 + it * 16 + cr;
        float4 v = *(const float4*)(x + ((size_t)(b * C_DIM + c)) * N_DIM + n0 + nq);
        u16* dst = xbfT + ((size_t)(b * N_DIM + n0 + nq)) * C_DIM + c;
        dst[0]   = f2bf(v.x);
        dst[256] = f2bf(v.y);
        dst[512] = f2bf(v.z);
        dst[768] = f2bf(v.w);
        float s = v.x + v.y + v.z + v.w;
        s += __shfl_xor(s, 1); s += __shfl_xor(s, 2);
        s += __shfl_xor(s, 4); s += __shfl_xor(s, 8);
        if ((t & 15) == 0) atomicAdd(&pooled[b * C_DIM + c], s);
    }
}

// ---- 3: SE MLP ----
__global__ void se_kernel(const float* __restrict__ pooled,
                          const float* __restrict__ fc1w, const float* __restrict__ fc1b,
                          const float* __restrict__ fc2w, const float* __restrict__ fc2b,
                          float* __restrict__ chw) {
    int b = blockIdx.x, t = threadIdx.x;
    __shared__ float sp[C_DIM], sh[R_DIM];
    sp[t] = pooled[b * C_DIM + t] * (1.f / N_DIM);
    __syncthreads();
    if (t < R_DIM) {
        float a = fc1b[t];
        for (int c = 0; c < C_DIM; ++c) a += sp[c] * fc1w[t * C_DIM + c];
        sh[t] = a > 0.f ? a : 0.f;
    }
    __syncthreads();
    float a = fc2b[t];
    for (int j = 0; j < R_DIM; ++j) a += sh[j] * fc2w[t * R_DIM + j];
    chw[b * C_DIM + t] = 1.f / (1.f + __builtin_amdgcn_exp2f(-a * 1.44269504089f));
}

// ---- 4: fused QKV projection ----
// theta [B,N,I] (pre-scaled by TH_SCALE), phiT [B,N,I], gT [B,I,N]
__global__ __launch_bounds__(256) void qkv_kernel(const u16* __restrict__ xbfT,
                                                  const u16* __restrict__ w3,
                                                  u16* __restrict__ theta,
                                                  u16* __restrict__ phiT,
                                                  u16* __restrict__ gT) {
    const int bid = blockIdx.x;
    const int b = bid & 7, nt = bid >> 3;
    const int n0 = nt * 64;
    const int t = threadIdx.x;
    const int lane = t & 63, w = t >> 6;
    const int col = lane & 15, quad = lane >> 4;
    const int colx = col & 7;

    __shared__ u16 AsF[64 * 256];  // [n][c], 16B-granule XOR-swizzled by (n&7)

    const u16* xb = xbfT + ((size_t)(b * N_DIM + n0)) * C_DIM;
    #pragma unroll
    for (int it = 0; it < 8; ++it) {
        int gl = it * 256 + t;
        int r = gl >> 5, pc = gl & 31;
        async16(xb + (size_t)r * C_DIM + ((pc ^ (r & 7)) << 3),
                &AsF[(it * 256 + w * 64) * 8]);
    }
    __syncthreads();

    const u16* arow = &AsF[(w * 16 + col) * 256];
    for (int z = 0; z < 3; ++z) {
        const u16* wz = w3 + z * (I_DIM * C_DIM);
        f32x4 acc[8];
        #pragma unroll
        for (int f = 0; f < 8; ++f) acc[f] = f32x4{0.f, 0.f, 0.f, 0.f};
        #pragma unroll
        for (int kc = 0; kc < 8; ++kc) {
            bf16x8 a = *(const bf16x8*)&arow[(((kc * 4 + quad) ^ colx)) << 3];
            #pragma unroll
            for (int f = 0; f < 8; ++f) {
                bf16x8 bfr = *(const bf16x8*)(wz + (size_t)(f * 16 + col) * C_DIM + kc * 32 + quad * 8);
                acc[f] = __builtin_amdgcn_mfma_f32_16x16x32_bf16(a, bfr, acc[f], 0, 0, 0);
            }
        }
        if (z == 0) {
            #pragma unroll
            for (int f = 0; f < 8; ++f)
                #pragma unroll
                for (int r = 0; r < 4; ++r) {
                    int n = n0 + w * 16 + quad * 4 + r;
                    theta[((size_t)(b * N_DIM) + n) * I_DIM + f * 16 + col] = f2bf(acc[f][r] * TH_SCALE);
                }
        } else if (z == 1) {
            #pragma unroll
            for (int f = 0; f < 8; ++f)
                #pragma unroll
                for (int r = 0; r < 4; ++r) {
                    int n = n0 + w * 16 + quad * 4 + r;
                    phiT[((size_t)(b * N_DIM) + n) * I_DIM + f * 16 + col] = f2bf(acc[f][r]);
                }
        } else {
            #pragma unroll
            for (int f = 0; f < 8; ++f) {
                unsigned lo = f2bf(acc[f][0]) | ((unsigned)f2bf(acc[f][1]) << 16);
                unsigned hi = f2bf(acc[f][2]) | ((unsigned)f2bf(acc[f][3]) << 16);
                uint2 pk; pk.x = lo; pk.y = hi;
                *(uint2*)(gT + ((size_t)(b * I_DIM) + f * 16 + col) * N_DIM + n0 + w * 16 + quad * 4) = pk;
            }
        }
    }
}

// ---- 5: flash attention (S^T form, fixed-max softmax) ----
__global__ __launch_bounds__(256) void attn_kernel(const u16* __restrict__ theta,
                                                   const u16* __restrict__ phiT,
                                                   const u16* __restrict__ gT,
                                                   u16* __restrict__ ao) {
    const int bid = blockIdx.x;
    const int b = bid & 7, qt = bid >> 3;   // XCD-bind: batch b pinned per XCD
    const int t = threadIdx.x;
    const int lane = t & 63, w = t >> 6;
    const int col = lane & 15, quad = lane >> 4;
    const int colx = col & 7;

    __shared__ u16 KsF[64 * 128];      // K-chunk [m][i], swizzled
    __shared__ u16 VsF[128 * 64];      // V^T chunk [i][m], swizzled
    __shared__ u16 PsF[4][16 * 64];    // per-wave P [q][m], swizzled

    // Q B-frags: B[k=i][n=q], q = col
    bf16x8 qf[4];
    {
        const u16* qp = theta + ((size_t)(b * N_DIM) + qt * 64 + w * 16 + col) * I_DIM + quad * 8;
        #pragma unroll
        for (int kc = 0; kc < 4; ++kc) qf[kc] = *(const bf16x8*)(qp + kc * 32);
    }

    const u16* kbase = phiT + (size_t)b * N_DIM * I_DIM;
    const u16* vbase = gT + (size_t)b * I_DIM * N_DIM;
    const u16* kptr[4];
    const u16* vptr[4];
    #pragma unroll
    for (int it = 0; it < 4; ++it) {
        int gl = it * 256 + t;
        int kr = gl >> 4, kp = gl & 15;
        kptr[it] = kbase + (size_t)kr * I_DIM + ((kp ^ (kr & 7)) << 3);
        int vi = gl >> 3, vp = gl & 7;
        vptr[it] = vbase + (size_t)vi * N_DIM + ((vp ^ (vi & 7)) << 3);
    }

    float plsum = 0.f;
    f32x4 oacc[8];
    #pragma unroll
    for (int f = 0; f < 8; ++f) oacc[f] = f32x4{0.f, 0.f, 0.f, 0.f};
    u16* Psw = PsF[w];

    for (int mc = 0; mc < 64; ++mc) {
        __syncthreads();   // protect K/V/P from overwrite while prev chunk in use
        #pragma unroll
        for (int it = 0; it < 4; ++it) {
            async16(kptr[it], &KsF[(it * 256 + w * 64) * 8]);
            kptr[it] += 64 * I_DIM;
        }
        #pragma unroll
        for (int it = 0; it < 4; ++it) {
            async16(vptr[it], &VsF[(it * 256 + w * 64) * 8]);
            vptr[it] += 64;
        }
        __syncthreads();   // drains vmcnt -> staged data visible

        // S^T tiles: D[m=quad*4+r][q=col] ; theta pre-scaled so P = exp2(S)
        #pragma unroll
        for (int ms = 0; ms < 4; ++ms) {
            f32x4 s = f32x4{0.f, 0.f, 0.f, 0.f};
            const u16* krow = &KsF[(ms * 16 + col) * 128];
            #pragma unroll
            for (int kc = 0; kc < 4; ++kc) {
                bf16x8 kf = *(const bf16x8*)&krow[((kc * 4 + quad) ^ colx) << 3];
                s = __builtin_amdgcn_mfma_f32_16x16x32_bf16(kf, qf[kc], s, 0, 0, 0);
            }
            float p0 = __builtin_amdgcn_exp2f(s[0]);
            float p1 = __builtin_amdgcn_exp2f(s[1]);
            float p2 = __builtin_amdgcn_exp2f(s[2]);
            float p3 = __builtin_amdgcn_exp2f(s[3]);
            plsum += (p0 + p1) + (p2 + p3);
            unsigned lo = f2bf(p0) | ((unsigned)f2bf(p1) << 16);
            unsigned hi = f2bf(p2) | ((unsigned)f2bf(p3) << 16);
            uint2 pk; pk.x = lo; pk.y = hi;
            int gm = ms * 2 + (quad >> 1);
            *(uint2*)&Psw[col * 64 + ((gm ^ colx) << 3) + ((quad & 1) << 2)] = pk;
        }
        // same-wave LDS write->read: in-order DS pipe; block compiler reordering + drain
        __asm__ volatile("s_waitcnt lgkmcnt(0)" ::: "memory");

        // O += P V : A = P[q=col][m], B = V^T[i][m]
        bf16x8 pf0 = *(const bf16x8*)&Psw[col * 64 + ((quad ^ colx) << 3)];
        bf16x8 pf1 = *(const bf16x8*)&Psw[col * 64 + (((quad + 4) ^ colx) << 3)];
        #pragma unroll
        for (int f = 0; f < 8; ++f) {
            const u16* vrow = &VsF[(f * 16 + col) * 64];
            bf16x8 vf0 = *(const bf16x8*)&vrow[((quad ^ colx)) << 3];
            bf16x8 vf1 = *(const bf16x8*)&vrow[(((quad + 4) ^ colx)) << 3];
            oacc[f] = __builtin_amdgcn_mfma_f32_16x16x32_bf16(pf0, vf0, oacc[f], 0, 0, 0);
            oacc[f] = __builtin_amdgcn_mfma_f32_16x16x32_bf16(pf1, vf1, oacc[f], 0, 0, 0);
        }
    }

    // final l reduce (over quad lanes) + cross-lane exchange via own-wave LDS
    plsum += __shfl_xor(plsum, 16);
    plsum += __shfl_xor(plsum, 32);
    float* lex = (float*)&PsF[w][0];
    if (quad == 0) lex[col] = plsum;
    __asm__ volatile("s_waitcnt lgkmcnt(0)" ::: "memory");
    #pragma unroll
    for (int r = 0; r < 4; ++r) {
        float linv = 1.f / lex[quad * 4 + r];
        int n = qt * 64 + w * 16 + quad * 4 + r;
        #pragma unroll
        for (int f = 0; f < 8; ++f)
            ao[((size_t)(b * N_DIM) + n) * I_DIM + f * 16 + col] = f2bf(oacc[f][r] * linv);
    }
}

// ---- 6: out projection (bf16 out2) + BN stats ----
__global__ __launch_bounds__(256) void oproj_kernel(const u16* __restrict__ ao,
                                                    const u16* __restrict__ owb,
                                                    u16* __restrict__ out2,
                                                    float* __restrict__ bnsum,
                                                    float* __restrict__ bnsumsq) {
    const int bid = blockIdx.x;
    const int b = bid & 7, nt = bid >> 3;
    const int t = threadIdx.x, lane = t & 63, w = t >> 6;
    const int col = lane & 15, quad = lane >> 4;
    const int n0 = nt * 64;

    __shared__ float lsum[C_DIM], lsq[C_DIM];
    lsum[t] = 0.f; lsq[t] = 0.f;
    __syncthreads();

    bf16x8 af[4];
    const u16* ap = ao + ((size_t)(b * N_DIM) + n0 + w * 16 + col) * I_DIM + quad * 8;
    #pragma unroll
    for (int kc = 0; kc < 4; ++kc) af[kc] = *(const bf16x8*)(ap + kc * 32);

    for (int f = 0; f < 16; ++f) {
        f32x4 acc = f32x4{0.f, 0.f, 0.f, 0.f};
        #pragma unroll
        for (int kc = 0; kc < 4; ++kc) {
            bf16x8 bfr = *(const bf16x8*)(owb + (size_t)(f * 16 + col) * I_DIM + kc * 32 + quad * 8);
            acc = __builtin_amdgcn_mfma_f32_16x16x32_bf16(af[kc], bfr, acc, 0, 0, 0);
        }
        int c = f * 16 + col;
        float s1 = (acc[0] + acc[1]) + (acc[2] + acc[3]);
        float s2 = (acc[0] * acc[0] + acc[1] * acc[1]) + (acc[2] * acc[2] + acc[3] * acc[3]);
        unsigned lo = f2bf(acc[0]) | ((unsigned)f2bf(acc[1]) << 16);
        unsigned hi = f2bf(acc[2]) | ((unsigned)f2bf(acc[3]) << 16);
        uint2 pk; pk.x = lo; pk.y = hi;
        *(uint2*)(out2 + ((size_t)(b * C_DIM) + c) * N_DIM + n0 + w * 16 + quad * 4) = pk;
        s1 += __shfl_xor(s1, 16); s2 += __shfl_xor(s2, 16);
        s1 += __shfl_xor(s1, 32); s2 += __shfl_xor(s2, 32);
        if (quad == 0) { atomicAdd(&lsum[c], s1); atomicAdd(&lsq[c], s2); }
    }
    __syncthreads();
    atomicAdd(&bnsum[t], lsum[t]);
    atomicAdd(&bnsumsq[t], lsq[t]);
}

// ---- 7: BN normalize + SE scale + residual ----
__global__ void final_kernel(const float* __restrict__ x, const u16* __restrict__ out2,
                             const float* __restrict__ bnsum, const float* __restrict__ bnsumsq,
                             const float* __restrict__ gamma, const float* __restrict__ beta,
                             const float* __restrict__ chw, float* __restrict__ out) {
    int idx = blockIdx.x * 256 + threadIdx.x;  // float4 index over [b][c][n]
    int e = idx * 4;
    int b = e >> 20;
    int c = (e >> 12) & 255;
    float mean = bnsum[c] * (1.f / 32768.f);
    float var  = bnsumsq[c] * (1.f / 32768.f) - mean * mean;
    float sc = gamma[c] * rsqrtf(var + 1e-5f);
    float sh = beta[c] - mean * sc;
    float cw = chw[b * C_DIM + c];
    ushort4 o16 = ((const ushort4*)out2)[idx];
    float4 xv = ((const float4*)x)[idx];
    float4 res;
    res.x = xv.x + (bf2f(o16.x) * sc + sh) * cw;
    res.y = xv.y + (bf2f(o16.y) * sc + sh) * cw;
    res.z = xv.z + (bf2f(o16.z) * sc + sh) * cw;
    res.w = xv.w + (bf2f(o16.w) * sc + sh) * cw;
    ((float4*)out)[idx] = res;
}

extern "C" void kernel_launch(void* const* d_in, const int* in_sizes, int n_in,
                              void* d_out, int out_size, void* d_ws, size_t ws_size,
                              hipStream_t stream) {
    const float* x   = (const float*)d_in[0];
    const float* tw  = (const float*)d_in[1];
    const float* pw  = (const float*)d_in[2];
    const float* gw  = (const float*)d_in[3];
    const float* ow  = (const float*)d_in[4];
    const float* gam = (const float*)d_in[5];
    const float* bet = (const float*)d_in[6];
    const float* f1w = (const float*)d_in[7];
    const float* f1b = (const float*)d_in[8];
    const float* f2w = (const float*)d_in[9];
    const float* f2b = (const float*)d_in[10];
    float* out = (float*)d_out;

    char* ws = (char*)d_ws;
    float* bnsum   = (float*)(ws + OFF_BNSUM);
    float* bnsumsq = (float*)(ws + OFF_BNSQ);
    float* pooled  = (float*)(ws + OFF_POOL);
    float* chw     = (float*)(ws + OFF_CHW);
    u16*   w3      = (u16*)(ws + OFF_W3);
    u16*   owb     = (u16*)(ws + OFF_OWB);
    u16*   xbt     = (u16*)(ws + OFF_XBT);
    u16*   theta   = (u16*)(ws + OFF_THETA);
    u16*   phiT    = (u16*)(ws + OFF_PHIT);
    u16*   gT      = (u16*)(ws + OFF_GT);
    u16*   ao      = (u16*)(ws + OFF_AO);
    u16*   out2    = (u16*)(ws + OFF_OUT2);

    prep_kernel<<<384, 256, 0, stream>>>(tw, pw, gw, ow, w3, owb, bnsum, pooled);
    xt_kernel<<<dim3(4, 64, 8), 256, 0, stream>>>(x, xbt, pooled);
    se_kernel<<<B_DIM, 256, 0, stream>>>(pooled, f1w, f1b, f2w, f2b, chw);
    qkv_kernel<<<512, 256, 0, stream>>>(xbt, w3, theta, phiT, gT);
    attn_kernel<<<512, 256, 0, stream>>>(theta, phiT, gT, ao);
    oproj_kernel<<<512, 256, 0, stream>>>(ao, owb, out2, bnsum, bnsumsq);
    final_kernel<<<8192, 256, 0, stream>>>(x, out2, bnsum, bnsumsq, gam, bet, chw, out);
}

// Round 4
// 294.552 us; speedup vs baseline: 1.3329x; 1.1445x over previous
//
#include <hip/hip_runtime.h>

#define B_DIM 8
#define C_DIM 256
#define I_DIM 128
#define N_DIM 4096
#define R_DIM 64

typedef unsigned short u16;
typedef unsigned int u32;
typedef __attribute__((ext_vector_type(8))) __bf16 bf16x8;
typedef __attribute__((ext_vector_type(4))) float f32x4;
typedef __attribute__((ext_vector_type(16))) float f32x16;

union BF8 { u32 u[4]; bf16x8 v; };

__device__ __forceinline__ u16 f2bf(float f) {
    union { float f; u32 u; } v; v.f = f;
    u32 r = v.u + 0x7FFFu + ((v.u >> 16) & 1u);
    return (u16)(r >> 16);
}
__device__ __forceinline__ float bf2f(u16 h) {
    union { u32 u; float f; } v; v.u = (u32)h << 16; return v.f;
}
__device__ __forceinline__ u32 pk2(float a, float b) {
    return (u32)f2bf(a) | ((u32)f2bf(b) << 16);
}
__device__ __forceinline__ void async16(const u16* g, u16* l) {
    __builtin_amdgcn_global_load_lds((const __attribute__((address_space(1))) void*)g,
                                     (__attribute__((address_space(3))) void*)l, 16, 0, 0);
}

// log2(e)/sqrt(128), folded into theta at projection time
#define TH_SCALE 0.1275204890136f

// ---- workspace layout (bytes) ----
static constexpr size_t OFF_BNSUM = 0;
static constexpr size_t OFF_BNSQ  = 1024;
static constexpr size_t OFF_POOL  = 2048;
static constexpr size_t OFF_CHW   = 10240;
static constexpr size_t OFF_W3    = 18432;                  // 3*128*256 bf16
static constexpr size_t OFF_OWB   = 215040;                 // 256*128 bf16
static constexpr size_t OFF_AO0   = 280576;                 // [B,N,I] bf16 partial 0
static constexpr size_t OFF_AO1   = OFF_AO0 + 8388608;      // partial 1
static constexpr size_t OFF_THETA = OFF_AO1 + 8388608;      // [B,N,I] bf16 (pre-scaled)
static constexpr size_t OFF_PHIT  = OFF_THETA + 8388608;
static constexpr size_t OFF_GT    = OFF_PHIT + 8388608;     // [B,I,N] bf16
static constexpr size_t OFF_L0    = OFF_GT + 8388608;       // [B,N] f32
static constexpr size_t OFF_L1    = OFF_L0 + 131072;
static constexpr size_t OFF_OUT2  = OFF_L1 + 131072;        // [B,C,N] bf16

// ---- 1: weight convert + zero BN stats ----
__global__ void prep_kernel(const float* __restrict__ tw, const float* __restrict__ pw,
                            const float* __restrict__ gw, const float* __restrict__ ow,
                            u16* __restrict__ w3, u16* __restrict__ owb,
                            float* __restrict__ bnzero) {
    int idx = blockIdx.x * 256 + threadIdx.x;
    if (idx < 512) bnzero[idx] = 0.f;
    if (idx < 3 * 32768) {
        const float* src = idx < 32768 ? tw : (idx < 65536 ? pw : gw);
        w3[idx] = f2bf(src[idx & 32767]);
    }
    if (idx < 32768) owb[idx] = f2bf(ow[idx]);
}

// ---- 2: SE pooling ----
__global__ void pool_kernel(const float* __restrict__ x, float* __restrict__ pooled) {
    int bc = blockIdx.x;
    const float4* row = (const float4*)(x + (size_t)bc * N_DIM);
    int t = threadIdx.x;
    float s = 0.f;
    for (int it = 0; it < 4; ++it) {
        float4 v = row[t + it * 256];
        s += v.x + v.y + v.z + v.w;
    }
    for (int d = 32; d; d >>= 1) s += __shfl_down(s, d);
    __shared__ float ls[4];
    if ((t & 63) == 0) ls[t >> 6] = s;
    __syncthreads();
    if (t == 0) pooled[bc] = (ls[0] + ls[1] + ls[2] + ls[3]) * (1.f / N_DIM);
}

// ---- 3: SE MLP ----
__global__ void se_kernel(const float* __restrict__ pooled,
                          const float* __restrict__ fc1w, const float* __restrict__ fc1b,
                          const float* __restrict__ fc2w, const float* __restrict__ fc2b,
                          float* __restrict__ chw) {
    int b = blockIdx.x, t = threadIdx.x;
    __shared__ float sp[C_DIM], sh[R_DIM];
    sp[t] = pooled[b * C_DIM + t];
    __syncthreads();
    if (t < R_DIM) {
        float a = fc1b[t];
        for (int c = 0; c < C_DIM; ++c) a += sp[c] * fc1w[t * C_DIM + c];
        sh[t] = a > 0.f ? a : 0.f;
    }
    __syncthreads();
    float a = fc2b[t];
    for (int j = 0; j < R_DIM; ++j) a += sh[j] * fc2w[t * R_DIM + j];
    chw[b * C_DIM + t] = 1.f / (1.f + __builtin_amdgcn_exp2f(-a * 1.44269504089f));
}

// ---- 4: fused QKV projection (direct from x, 32x32x16 MFMA) ----
// K-depth: C=256 -> 16 MFMA steps of K=16 (granule 2*ks+h spans all 32 granules)
__global__ __launch_bounds__(256) void qkv_kernel(const float* __restrict__ x,
                                                  const u16* __restrict__ w3,
                                                  u16* __restrict__ theta,
                                                  u16* __restrict__ phiT,
                                                  u16* __restrict__ gT) {
    const int bid = blockIdx.x;
    const int b = bid & 7, nt = bid >> 3;
    const int n0 = nt * 64;
    const int t = threadIdx.x, lane = t & 63, w = t >> 6;
    const int cl = lane & 31, h = lane >> 5;

    __shared__ u16 As[64 * 256];   // [n][c] bf16, 16B-granule swizzled ^(n&7)
    __shared__ u16 Ep[128 * 72];   // epilogue buffer

    {   // stage x[b, :, n0:n0+64] -> As (transposed to [n][c])
        const float* xb = x + ((size_t)b * C_DIM) * N_DIM + n0;
        for (int it = 0; it < 16; ++it) {
            int id = it * 256 + t;
            int c = id >> 4, l16 = id & 15;
            float4 v = *(const float4*)(xb + (size_t)c * N_DIM + l16 * 4);
            int g = c >> 3, co = c & 7;
            float vv[4] = {v.x, v.y, v.z, v.w};
            #pragma unroll
            for (int k = 0; k < 4; ++k) {
                int n = l16 * 4 + k;
                As[n * 256 + ((g ^ (n & 7)) << 3) + co] = f2bf(vv[k]);
            }
        }
    }
    __syncthreads();

    const int mt = w & 1;    // n-tile
    const int ip = w >> 1;   // i-pair
    bf16x8 afr[16];
    #pragma unroll
    for (int ks = 0; ks < 16; ++ks) {
        int r = mt * 32 + cl;
        int g = 2 * ks + h;
        afr[ks] = *(const bf16x8*)&As[r * 256 + ((g ^ (r & 7)) << 3)];
    }

    for (int z = 0; z < 3; ++z) {
        const u16* wz = w3 + z * (I_DIM * C_DIM);
        f32x16 acc[2] = {};
        #pragma unroll
        for (int ks = 0; ks < 16; ++ks) {
            #pragma unroll
            for (int f = 0; f < 2; ++f) {
                int irow = (2 * ip + f) * 32 + cl;
                bf16x8 bfr = *(const bf16x8*)(wz + (size_t)irow * C_DIM + ks * 16 + h * 8);
                acc[f] = __builtin_amdgcn_mfma_f32_32x32x16_bf16(afr[ks], bfr, acc[f], 0, 0, 0);
            }
        }
        if (z < 2) {
            float sc = (z == 0) ? TH_SCALE : 1.0f;
            // Ep as [n64][i 136pad]
            #pragma unroll
            for (int f = 0; f < 2; ++f) {
                int i = (2 * ip + f) * 32 + cl;
                #pragma unroll
                for (int r2 = 0; r2 < 4; ++r2)
                    #pragma unroll
                    for (int e = 0; e < 4; ++e) {
                        int n = mt * 32 + 8 * r2 + 4 * h + e;
                        Ep[n * 136 + i] = f2bf(acc[f][4 * r2 + e] * sc);
                    }
            }
            __syncthreads();
            u16* dst = (z == 0) ? theta : phiT;
            #pragma unroll
            for (int it = 0; it < 4; ++it) {
                int id = it * 256 + t;
                int n = id >> 4, l16 = id & 15;
                f32x4 vv = *(const f32x4*)&Ep[n * 136 + l16 * 8];
                *(f32x4*)(dst + ((size_t)(b * N_DIM) + n0 + n) * I_DIM + l16 * 8) = vv;
            }
            __syncthreads();
        } else {
            // Ep as [i128][n 72pad]
            #pragma unroll
            for (int f = 0; f < 2; ++f) {
                int i = (2 * ip + f) * 32 + cl;
                #pragma unroll
                for (int r2 = 0; r2 < 4; ++r2) {
                    u32 lo = pk2(acc[f][4 * r2 + 0], acc[f][4 * r2 + 1]);
                    u32 hi = pk2(acc[f][4 * r2 + 2], acc[f][4 * r2 + 3]);
                    int nb = mt * 32 + 8 * r2 + 4 * h;
                    *(u32*)&Ep[i * 72 + nb] = lo;
                    *(u32*)&Ep[i * 72 + nb + 2] = hi;
                }
            }
            __syncthreads();
            #pragma unroll
            for (int it = 0; it < 4; ++it) {
                int id = it * 256 + t;
                int i = id >> 3, l8 = id & 7;
                f32x4 vv = *(const f32x4*)&Ep[i * 72 + l8 * 8];
                *(f32x4*)(gT + ((size_t)(b * I_DIM) + i) * N_DIM + n0 + l8 * 8) = vv;
            }
        }
    }
}

// ---- 5: flash attention, 32x32 MFMA, q=32/wave, m-split 2, register P-exchange ----
__global__ __launch_bounds__(256) void attn_kernel(const u16* __restrict__ theta,
                                                   const u16* __restrict__ phiT,
                                                   const u16* __restrict__ gT,
                                                   u16* __restrict__ ao0, u16* __restrict__ ao1,
                                                   float* __restrict__ l0, float* __restrict__ l1) {
    const int bid = blockIdx.x;
    const int b = bid & 7, mh = (bid >> 3) & 1, qt = bid >> 4;
    const int t = threadIdx.x, lane = t & 63, w = t >> 6;
    const int cl = lane & 31, h = lane >> 5;
    const int qw = qt * 128 + w * 32;    // wave q-base

    __shared__ u16 SM[16384];            // Ks 16KB | Vs 16KB  (reused for ao epilogue)
    __shared__ float lex[4][32];
    u16* Ks = SM;
    u16* Vs = SM + 8192;

    bf16x8 qf[8];
    {
        const u16* qp = theta + ((size_t)(b * N_DIM) + qw + cl) * I_DIM + h * 8;
        #pragma unroll
        for (int ks = 0; ks < 8; ++ks) qf[ks] = *(const bf16x8*)(qp + ks * 16);
    }

    const u16* kbase = phiT + (size_t)b * N_DIM * I_DIM + (size_t)(mh * 2048) * I_DIM;
    const u16* vbase = gT + (size_t)b * I_DIM * N_DIM + mh * 2048;
    const u16* kptr[4]; const u16* vptr[4];
    #pragma unroll
    for (int it = 0; it < 4; ++it) {
        int gi = (w * 4 + it) * 64 + lane;
        int kr = gi >> 4, kg = gi & 15;
        kptr[it] = kbase + (size_t)kr * I_DIM + ((kg ^ (kr & 7)) << 3);
        int vr = gi >> 3, vg = gi & 7;
        vptr[it] = vbase + (size_t)vr * N_DIM + ((vg ^ (vr & 7)) << 3);
    }

    float lsum = 0.f;
    f32x16 O[4] = {};

    for (int mc = 0; mc < 32; ++mc) {
        __syncthreads();
        #pragma unroll
        for (int it = 0; it < 4; ++it) { async16(kptr[it], Ks + (w * 4 + it) * 512); kptr[it] += 64 * I_DIM; }
        #pragma unroll
        for (int it = 0; it < 4; ++it) { async16(vptr[it], Vs + (w * 4 + it) * 512); vptr[it] += 64; }
        __syncthreads();

        // S^T = K Q^T (row=m, col=q); theta pre-scaled so P = exp2(S)
        u32 pk[8][2];
        #pragma unroll
        for (int mt2 = 0; mt2 < 2; ++mt2) {
            f32x16 S = {};
            #pragma unroll
            for (int ks = 0; ks < 8; ++ks) {
                int r = mt2 * 32 + cl;
                bf16x8 kf = *(const bf16x8*)&Ks[r * 128 + (((2 * ks + h) ^ (r & 7)) << 3)];
                S = __builtin_amdgcn_mfma_f32_32x32x16_bf16(kf, qf[ks], S, 0, 0, 0);
            }
            #pragma unroll
            for (int r2 = 0; r2 < 4; ++r2) {
                float p0 = __builtin_amdgcn_exp2f(S[4 * r2 + 0]);
                float p1 = __builtin_amdgcn_exp2f(S[4 * r2 + 1]);
                float p2 = __builtin_amdgcn_exp2f(S[4 * r2 + 2]);
                float p3 = __builtin_amdgcn_exp2f(S[4 * r2 + 3]);
                lsum += (p0 + p1) + (p2 + p3);
                pk[mt2 * 4 + r2][0] = pk2(p0, p1);
                pk[mt2 * 4 + r2][1] = pk2(p2, p3);
            }
        }

        // O += P V ; A-frag assembled via shfl_xor(32) exchange (no LDS)
        #pragma unroll
        for (int ks = 0; ks < 4; ++ks) {
            u32 a0 = pk[2 * ks][0], a1 = pk[2 * ks][1];
            u32 b0 = pk[2 * ks + 1][0], b1 = pk[2 * ks + 1][1];
            bool hb = (h != 0);
            u32 own0 = hb ? b0 : a0, own1 = hb ? b1 : a1;
            u32 xf0 = hb ? a0 : b0, xf1 = hb ? a1 : b1;
            u32 rc0 = (u32)__shfl_xor((int)xf0, 32);
            u32 rc1 = (u32)__shfl_xor((int)xf1, 32);
            BF8 A;
            A.u[0] = hb ? rc0 : own0;
            A.u[1] = hb ? rc1 : own1;
            A.u[2] = hb ? own0 : rc0;
            A.u[3] = hb ? own1 : rc1;
            #pragma unroll
            for (int f = 0; f < 4; ++f) {
                int ir = f * 32 + cl;
                bf16x8 vf = *(const bf16x8*)&Vs[ir * 64 + (((2 * ks + h) ^ (ir & 7)) << 3)];
                O[f] = __builtin_amdgcn_mfma_f32_32x32x16_bf16(A.v, vf, O[f], 0, 0, 0);
            }
        }
    }

    // l totals (lane holds q = cl's column sums split across halves)
    lsum += __shfl_xor(lsum, 32);
    if (h == 0) lex[w][cl] = lsum;
    __syncthreads();   // lex visible + SM free for reuse

    float linv[16];
    {
        float* lw = lex[w];
        #pragma unroll
        for (int r2 = 0; r2 < 4; ++r2) {
            f32x4 lv = *(const f32x4*)&lw[8 * r2 + 4 * h];
            #pragma unroll
            for (int e = 0; e < 4; ++e) linv[4 * r2 + e] = 1.f / lv[e];
        }
    }

    u16* aop = (mh == 0) ? ao0 : ao1;
    float* lp = (mh == 0) ? l0 : l1;
    if (h == 0) lp[(size_t)b * N_DIM + qw + cl] = lsum;

    u16* ep = SM + w * 4096;   // [q32][i128] per wave
    #pragma unroll
    for (int f = 0; f < 4; ++f)
        #pragma unroll
        for (int r2 = 0; r2 < 4; ++r2)
            #pragma unroll
            for (int e = 0; e < 4; ++e) {
                int q = 8 * r2 + 4 * h + e;
                ep[q * 128 + f * 32 + cl] = f2bf(O[f][4 * r2 + e] * linv[4 * r2 + e]);
            }
    __asm__ volatile("s_waitcnt lgkmcnt(0)" ::: "memory");
    #pragma unroll
    for (int it = 0; it < 8; ++it) {
        int id = it * 64 + lane;
        int q = id >> 4, l16 = id & 15;
        f32x4 vv = *(const f32x4*)&ep[q * 128 + l16 * 8];
        *(f32x4*)(aop + ((size_t)(b * N_DIM) + qw + q) * I_DIM + l16 * 8) = vv;
    }
}

// ---- 6: out projection + partial combine + BN stats ----
__global__ __launch_bounds__(256) void oproj_kernel(const u16* __restrict__ ao0,
                                                    const u16* __restrict__ ao1,
                                                    const float* __restrict__ l0,
                                                    const float* __restrict__ l1,
                                                    const u16* __restrict__ owb,
                                                    u16* __restrict__ out2,
                                                    float* __restrict__ bnsum,
                                                    float* __restrict__ bnsumsq) {
    const int bid = blockIdx.x;
    const int b = bid & 7, nt = bid >> 3;
    const int n0 = nt * 64;
    const int t = threadIdx.x, lane = t & 63, w = t >> 6;
    const int cl = lane & 31, h = lane >> 5;

    __shared__ u16 Ep[256 * 72];   // [c][n 72pad]
    __shared__ float lsum[C_DIM], lsq[C_DIM];
    lsum[t] = 0.f; lsq[t] = 0.f;
    __syncthreads();

    const int mt = w & 1;
    const int nn = n0 + mt * 32 + cl;
    float w0, w1;
    {
        float la = l0[(size_t)b * N_DIM + nn], lb = l1[(size_t)b * N_DIM + nn];
        float inv = 1.f / (la + lb);
        w0 = la * inv; w1 = lb * inv;
    }
    bf16x8 afr[8];
    {
        const u16* p0 = ao0 + ((size_t)(b * N_DIM) + nn) * I_DIM + h * 8;
        const u16* p1 = ao1 + ((size_t)(b * N_DIM) + nn) * I_DIM + h * 8;
        #pragma unroll
        for (int ks = 0; ks < 8; ++ks) {
            bf16x8 x0 = *(const bf16x8*)(p0 + ks * 16);
            bf16x8 x1 = *(const bf16x8*)(p1 + ks * 16);
            const u16* u0 = (const u16*)&x0;
            const u16* u1 = (const u16*)&x1;
            float c0 = w0 * bf2f(u0[0]) + w1 * bf2f(u1[0]);
            float c1 = w0 * bf2f(u0[1]) + w1 * bf2f(u1[1]);
            float c2 = w0 * bf2f(u0[2]) + w1 * bf2f(u1[2]);
            float c3 = w0 * bf2f(u0[3]) + w1 * bf2f(u1[3]);
            float c4 = w0 * bf2f(u0[4]) + w1 * bf2f(u1[4]);
            float c5 = w0 * bf2f(u0[5]) + w1 * bf2f(u1[5]);
            float c6 = w0 * bf2f(u0[6]) + w1 * bf2f(u1[6]);
            float c7 = w0 * bf2f(u0[7]) + w1 * bf2f(u1[7]);
            BF8 r;
            r.u[0] = pk2(c0, c1); r.u[1] = pk2(c2, c3);
            r.u[2] = pk2(c4, c5); r.u[3] = pk2(c6, c7);
            afr[ks] = r.v;
        }
    }

    f32x16 D[4] = {};
    #pragma unroll
    for (int ks = 0; ks < 8; ++ks) {
        #pragma unroll
        for (int j = 0; j < 4; ++j) {
            int cr = ((w >> 1) * 4 + j) * 32 + cl;
            bf16x8 bfr = *(const bf16x8*)(owb + (size_t)cr * I_DIM + ks * 16 + h * 8);
            D[j] = __builtin_amdgcn_mfma_f32_32x32x16_bf16(afr[ks], bfr, D[j], 0, 0, 0);
        }
    }

    #pragma unroll
    for (int j = 0; j < 4; ++j) {
        int c = ((w >> 1) * 4 + j) * 32 + cl;
        float s1 = 0.f, s2 = 0.f;
        #pragma unroll
        for (int r2 = 0; r2 < 4; ++r2) {
            float v0 = D[j][4 * r2 + 0], v1 = D[j][4 * r2 + 1];
            float v2 = D[j][4 * r2 + 2], v3 = D[j][4 * r2 + 3];
            s1 += (v0 + v1) + (v2 + v3);
            s2 += (v0 * v0 + v1 * v1) + (v2 * v2 + v3 * v3);
            int nb = mt * 32 + 8 * r2 + 4 * h;
            *(u32*)&Ep[c * 72 + nb] = pk2(v0, v1);
            *(u32*)&Ep[c * 72 + nb + 2] = pk2(v2, v3);
        }
        atomicAdd(&lsum[c], s1);
        atomicAdd(&lsq[c], s2);
    }
    __syncthreads();
    #pragma unroll
    for (int it = 0; it < 8; ++it) {
        int id = it * 256 + t;
        int c = id >> 3, l8 = id & 7;
        f32x4 vv = *(const f32x4*)&Ep[c * 72 + l8 * 8];
        *(f32x4*)(out2 + ((size_t)(b * C_DIM) + c) * N_DIM + n0 + l8 * 8) = vv;
    }
    atomicAdd(&bnsum[t], lsum[t]);
    atomicAdd(&bnsumsq[t], lsq[t]);
}

// ---- 7: BN normalize + SE scale + residual ----
__global__ void final_kernel(const float* __restrict__ x, const u16* __restrict__ out2,
                             const float* __restrict__ bnsum, const float* __restrict__ bnsumsq,
                             const float* __restrict__ gamma, const float* __restrict__ beta,
                             const float* __restrict__ chw, float* __restrict__ out) {
    int idx = blockIdx.x * 256 + threadIdx.x;
    int e = idx * 4;
    int b = e >> 20;
    int c = (e >> 12) & 255;
    float mean = bnsum[c] * (1.f / 32768.f);
    float var = bnsumsq[c] * (1.f / 32768.f) - mean * mean;
    float sc = gamma[c] * rsqrtf(var + 1e-5f);
    float sh = beta[c] - mean * sc;
    float cw = chw[b * C_DIM + c];
    ushort4 o16 = ((const ushort4*)out2)[idx];
    float4 xv = ((const float4*)x)[idx];
    float4 res;
    res.x = xv.x + (bf2f(o16.x) * sc + sh) * cw;
    res.y = xv.y + (bf2f(o16.y) * sc + sh) * cw;
    res.z = xv.z + (bf2f(o16.z) * sc + sh) * cw;
    res.w = xv.w + (bf2f(o16.w) * sc + sh) * cw;
    ((float4*)out)[idx] = res;
}

extern "C" void kernel_launch(void* const* d_in, const int* in_sizes, int n_in,
                              void* d_out, int out_size, void* d_ws, size_t ws_size,
                              hipStream_t stream) {
    const float* x   = (const float*)d_in[0];
    const float* tw  = (const float*)d_in[1];
    const float* pw  = (const float*)d_in[2];
    const float* gw  = (const float*)d_in[3];
    const float* ow  = (const float*)d_in[4];
    const float* gam = (const float*)d_in[5];
    const float* bet = (const float*)d_in[6];
    const float* f1w = (const float*)d_in[7];
    const float* f1b = (const float*)d_in[8];
    const float* f2w = (const float*)d_in[9];
    const float* f2b = (const float*)d_in[10];
    float* out = (float*)d_out;

    char* ws = (char*)d_ws;
    float* bnsum   = (float*)(ws + OFF_BNSUM);
    float* bnsumsq = (float*)(ws + OFF_BNSQ);
    float* pooled  = (float*)(ws + OFF_POOL);
    float* chw     = (float*)(ws + OFF_CHW);
    u16*   w3      = (u16*)(ws + OFF_W3);
    u16*   owb     = (u16*)(ws + OFF_OWB);
    u16*   ao0     = (u16*)(ws + OFF_AO0);
    u16*   ao1     = (u16*)(ws + OFF_AO1);
    u16*   theta   = (u16*)(ws + OFF_THETA);
    u16*   phiT    = (u16*)(ws + OFF_PHIT);
    u16*   gT      = (u16*)(ws + OFF_GT);
    float* l0      = (float*)(ws + OFF_L0);
    float* l1      = (float*)(ws + OFF_L1);
    u16*   out2    = (u16*)(ws + OFF_OUT2);

    prep_kernel<<<384, 256, 0, stream>>>(tw, pw, gw, ow, w3, owb, bnsum);
    pool_kernel<<<B_DIM * C_DIM, 256, 0, stream>>>(x, pooled);
    se_kernel<<<B_DIM, 256, 0, stream>>>(pooled, f1w, f1b, f2w, f2b, chw);
    qkv_kernel<<<512, 256, 0, stream>>>(x, w3, theta, phiT, gT);
    attn_kernel<<<512, 256, 0, stream>>>(theta, phiT, gT, ao0, ao1, l0, l1);
    oproj_kernel<<<512, 256, 0, stream>>>(ao0, ao1, l0, l1, owb, out2, bnsum, bnsumsq);
    final_kernel<<<8192, 256, 0, stream>>>(x, out2, bnsum, bnsumsq, gam, bet, chw, out);
}

// Round 5
// 270.383 us; speedup vs baseline: 1.4520x; 1.0894x over previous
//
#include <hip/hip_runtime.h>

#define B_DIM 8
#define C_DIM 256
#define I_DIM 128
#define N_DIM 4096
#define R_DIM 64

typedef unsigned short u16;
typedef unsigned int u32;
typedef __attribute__((ext_vector_type(8))) __bf16 bf16x8;
typedef __attribute__((ext_vector_type(4))) float f32x4;
typedef __attribute__((ext_vector_type(16))) float f32x16;

union BF8 { u32 u[4]; bf16x8 v; };

__device__ __forceinline__ u16 f2bf(float f) {
    union { float f; u32 u; } v; v.f = f;
    u32 r = v.u + 0x7FFFu + ((v.u >> 16) & 1u);
    return (u16)(r >> 16);
}
__device__ __forceinline__ float bf2f(u16 h) {
    union { u32 u; float f; } v; v.u = (u32)h << 16; return v.f;
}
__device__ __forceinline__ u32 pk2(float a, float b) {
    return (u32)f2bf(a) | ((u32)f2bf(b) << 16);
}
// truncating bf16 pack: [b.hi16 | a.hi16] in ONE v_perm_b32
__device__ __forceinline__ u32 pk2t(float a, float b) {
    union { float f; u32 u; } ua, ub; ua.f = a; ub.f = b;
    return __builtin_amdgcn_perm(ub.u, ua.u, 0x07060302u);
}
__device__ __forceinline__ void async16(const u16* g, u16* l) {
    __builtin_amdgcn_global_load_lds((const __attribute__((address_space(1))) void*)g,
                                     (__attribute__((address_space(3))) void*)l, 16, 0, 0);
}

// log2(e)/sqrt(128), folded into theta at projection time
#define TH_SCALE 0.1275204890136f

// ---- workspace layout (bytes) ----
static constexpr size_t OFF_BNSUM = 0;
static constexpr size_t OFF_BNSQ  = 1024;
static constexpr size_t OFF_POOL  = 2048;
static constexpr size_t OFF_CHW   = 10240;
static constexpr size_t OFF_W3    = 18432;                  // 3*128*256 bf16
static constexpr size_t OFF_OWB   = 215040;                 // 256*128 bf16
static constexpr size_t OFF_AO0   = 280576;                 // [B,N,I] bf16 partial 0
static constexpr size_t OFF_AO1   = OFF_AO0 + 8388608;      // partial 1
static constexpr size_t OFF_THETA = OFF_AO1 + 8388608;      // [B,N,I] bf16 (pre-scaled)
static constexpr size_t OFF_PHIT  = OFF_THETA + 8388608;
static constexpr size_t OFF_GT    = OFF_PHIT + 8388608;     // [B,I,N] bf16
static constexpr size_t OFF_L0    = OFF_GT + 8388608;       // [B,N] f32
static constexpr size_t OFF_L1    = OFF_L0 + 131072;
static constexpr size_t OFF_OUT2  = OFF_L1 + 131072;        // [B,C,N] bf16

// ---- 1: weight convert + zero accumulators ----
__global__ void prep_kernel(const float* __restrict__ tw, const float* __restrict__ pw,
                            const float* __restrict__ gw, const float* __restrict__ ow,
                            u16* __restrict__ w3, u16* __restrict__ owb,
                            float* __restrict__ bnzero, float* __restrict__ pooled) {
    int idx = blockIdx.x * 256 + threadIdx.x;
    if (idx < 512) bnzero[idx] = 0.f;
    if (idx < 2048) pooled[idx] = 0.f;
    if (idx < 3 * 32768) {
        const float* src = idx < 32768 ? tw : (idx < 65536 ? pw : gw);
        w3[idx] = f2bf(src[idx & 32767]);
    }
    if (idx < 32768) owb[idx] = f2bf(ow[idx]);
}

// ---- 3: SE MLP (runs after qkv, which accumulates pooled sums) ----
__global__ void se_kernel(const float* __restrict__ pooled,
                          const float* __restrict__ fc1w, const float* __restrict__ fc1b,
                          const float* __restrict__ fc2w, const float* __restrict__ fc2b,
                          float* __restrict__ chw) {
    int b = blockIdx.x, t = threadIdx.x;
    __shared__ float sp[C_DIM], sh[R_DIM];
    sp[t] = pooled[b * C_DIM + t] * (1.f / N_DIM);
    __syncthreads();
    if (t < R_DIM) {
        float a = fc1b[t];
        for (int c = 0; c < C_DIM; ++c) a += sp[c] * fc1w[t * C_DIM + c];
        sh[t] = a > 0.f ? a : 0.f;
    }
    __syncthreads();
    float a = fc2b[t];
    for (int j = 0; j < R_DIM; ++j) a += sh[j] * fc2w[t * R_DIM + j];
    chw[b * C_DIM + t] = 1.f / (1.f + __builtin_amdgcn_exp2f(-a * 1.44269504089f));
}

// ---- 4: fused QKV projection (direct from x, 32x32x16 MFMA) + SE pooling ----
__global__ __launch_bounds__(256) void qkv_kernel(const float* __restrict__ x,
                                                  const u16* __restrict__ w3,
                                                  u16* __restrict__ theta,
                                                  u16* __restrict__ phiT,
                                                  u16* __restrict__ gT,
                                                  float* __restrict__ pooled) {
    const int bid = blockIdx.x;
    const int b = bid & 7, nt = bid >> 3;
    const int n0 = nt * 64;
    const int t = threadIdx.x, lane = t & 63, w = t >> 6;
    const int cl = lane & 31, h = lane >> 5;

    __shared__ u16 As[64 * 256];   // [n][c] bf16, 16B-granule swizzled ^(n&7)
    __shared__ u16 Ep[128 * 72];   // epilogue buffer

    {   // stage x[b, :, n0:n0+64] -> As (transposed to [n][c]); fused SE pooling
        const float* xb = x + ((size_t)b * C_DIM) * N_DIM + n0;
        for (int it = 0; it < 16; ++it) {
            int id = it * 256 + t;
            int c = id >> 4, l16 = id & 15;
            float4 v = *(const float4*)(xb + (size_t)c * N_DIM + l16 * 4);
            int g = c >> 3, co = c & 7;
            float vv[4] = {v.x, v.y, v.z, v.w};
            #pragma unroll
            for (int k = 0; k < 4; ++k) {
                int n = l16 * 4 + k;
                As[n * 256 + ((g ^ (n & 7)) << 3) + co] = f2bf(vv[k]);
            }
            float s = (v.x + v.y) + (v.z + v.w);
            s += __shfl_xor(s, 1); s += __shfl_xor(s, 2);
            s += __shfl_xor(s, 4); s += __shfl_xor(s, 8);
            if ((t & 15) == 0) atomicAdd(&pooled[b * C_DIM + c], s);
        }
    }
    __syncthreads();

    const int mt = w & 1;    // n-tile
    const int ip = w >> 1;   // i-pair
    bf16x8 afr[16];
    #pragma unroll
    for (int ks = 0; ks < 16; ++ks) {
        int r = mt * 32 + cl;
        int g = 2 * ks + h;
        afr[ks] = *(const bf16x8*)&As[r * 256 + ((g ^ (r & 7)) << 3)];
    }

    for (int z = 0; z < 3; ++z) {
        const u16* wz = w3 + z * (I_DIM * C_DIM);
        f32x16 acc[2] = {};
        #pragma unroll
        for (int ks = 0; ks < 16; ++ks) {
            #pragma unroll
            for (int f = 0; f < 2; ++f) {
                int irow = (2 * ip + f) * 32 + cl;
                bf16x8 bfr = *(const bf16x8*)(wz + (size_t)irow * C_DIM + ks * 16 + h * 8);
                acc[f] = __builtin_amdgcn_mfma_f32_32x32x16_bf16(afr[ks], bfr, acc[f], 0, 0, 0);
            }
        }
        if (z < 2) {
            float sc = (z == 0) ? TH_SCALE : 1.0f;
            // Ep as [n64][i 136pad]
            #pragma unroll
            for (int f = 0; f < 2; ++f) {
                int i = (2 * ip + f) * 32 + cl;
                #pragma unroll
                for (int r2 = 0; r2 < 4; ++r2)
                    #pragma unroll
                    for (int e = 0; e < 4; ++e) {
                        int n = mt * 32 + 8 * r2 + 4 * h + e;
                        Ep[n * 136 + i] = f2bf(acc[f][4 * r2 + e] * sc);
                    }
            }
            __syncthreads();
            u16* dst = (z == 0) ? theta : phiT;
            #pragma unroll
            for (int it = 0; it < 4; ++it) {
                int id = it * 256 + t;
                int n = id >> 4, l16 = id & 15;
                f32x4 vv = *(const f32x4*)&Ep[n * 136 + l16 * 8];
                *(f32x4*)(dst + ((size_t)(b * N_DIM) + n0 + n) * I_DIM + l16 * 8) = vv;
            }
            __syncthreads();
        } else {
            // Ep as [i128][n 72pad]
            #pragma unroll
            for (int f = 0; f < 2; ++f) {
                int i = (2 * ip + f) * 32 + cl;
                #pragma unroll
                for (int r2 = 0; r2 < 4; ++r2) {
                    u32 lo = pk2(acc[f][4 * r2 + 0], acc[f][4 * r2 + 1]);
                    u32 hi = pk2(acc[f][4 * r2 + 2], acc[f][4 * r2 + 3]);
                    int nb = mt * 32 + 8 * r2 + 4 * h;
                    *(u32*)&Ep[i * 72 + nb] = lo;
                    *(u32*)&Ep[i * 72 + nb + 2] = hi;
                }
            }
            __syncthreads();
            #pragma unroll
            for (int it = 0; it < 4; ++it) {
                int id = it * 256 + t;
                int i = id >> 3, l8 = id & 7;
                f32x4 vv = *(const f32x4*)&Ep[i * 72 + l8 * 8];
                *(f32x4*)(gT + ((size_t)(b * I_DIM) + i) * N_DIM + n0 + l8 * 8) = vv;
            }
        }
    }
}

// ---- 5: flash attention, 32x32 MFMA, double-buffered K/V with in-flight prefetch ----
// Pipeline: raw s_barrier + s_waitcnt vmcnt(8) — prefetch loads stay in flight
// across the barrier (AITER-style); only the last chunk drains vmcnt(0).
__global__ __launch_bounds__(256) void attn_kernel(const u16* __restrict__ theta,
                                                   const u16* __restrict__ phiT,
                                                   const u16* __restrict__ gT,
                                                   u16* __restrict__ ao0, u16* __restrict__ ao1,
                                                   float* __restrict__ l0, float* __restrict__ l1) {
    const int bid = blockIdx.x;
    const int b = bid & 7, mh = (bid >> 3) & 1, qt = bid >> 4;
    const int t = threadIdx.x, lane = t & 63, w = t >> 6;
    const int cl = lane & 31, h = lane >> 5;
    const int qw = qt * 128 + w * 32;    // wave q-base

    __shared__ u16 SM[32768];            // 64KB: K0[0,8192) V0[8192,16384) K1 V1
    __shared__ float lex[4][32];

    bf16x8 qf[8];
    {
        const u16* qp = theta + ((size_t)(b * N_DIM) + qw + cl) * I_DIM + h * 8;
        #pragma unroll
        for (int ks = 0; ks < 8; ++ks) qf[ks] = *(const bf16x8*)(qp + ks * 16);
    }

    const u16* kbase = phiT + (size_t)b * N_DIM * I_DIM + (size_t)(mh * 2048) * I_DIM;
    const u16* vbase = gT + (size_t)b * I_DIM * N_DIM + mh * 2048;
    const u16* kptr[4]; const u16* vptr[4];
    #pragma unroll
    for (int it = 0; it < 4; ++it) {
        int gi = (w * 4 + it) * 64 + lane;
        int kr = gi >> 4, kg = gi & 15;
        kptr[it] = kbase + (size_t)kr * I_DIM + ((kg ^ (kr & 7)) << 3);
        int vr = gi >> 3, vg = gi & 7;
        vptr[it] = vbase + (size_t)vr * N_DIM + ((vg ^ (vr & 7)) << 3);
    }

    auto issue = [&](int p) {
        u16* Kd = SM + p * 16384;
        u16* Vd = SM + p * 16384 + 8192;
        #pragma unroll
        for (int it = 0; it < 4; ++it) { async16(kptr[it], Kd + (w * 4 + it) * 512); kptr[it] += 64 * I_DIM; }
        #pragma unroll
        for (int it = 0; it < 4; ++it) { async16(vptr[it], Vd + (w * 4 + it) * 512); vptr[it] += 64; }
    };

    float lsum = 0.f;
    f32x16 O[4] = {};

    issue(0);   // chunk 0 -> buf 0

    for (int mc = 0; mc < 32; ++mc) {
        const int p = mc & 1;
        // (A) all waves done computing chunk mc-1 -> buf 1-p is free to overwrite
        __asm__ volatile("s_barrier" ::: "memory");
        if (mc < 31) {
            issue(1 - p);   // prefetch chunk mc+1; stays in flight across barrier B
            __asm__ volatile("s_waitcnt vmcnt(8)" ::: "memory");   // own chunk-mc loads retired
        } else {
            __asm__ volatile("s_waitcnt vmcnt(0)" ::: "memory");
        }
        // (B) all waves' chunk-mc loads retired -> buf p fully populated
        __asm__ volatile("s_barrier" ::: "memory");

        const u16* Ks = SM + p * 16384;
        const u16* Vs = SM + p * 16384 + 8192;

        // S^T = K Q^T (row=m, col=q); theta pre-scaled so P = exp2(S)
        u32 pk[8][2];
        #pragma unroll
        for (int mt2 = 0; mt2 < 2; ++mt2) {
            f32x16 S = {};
            #pragma unroll
            for (int ks = 0; ks < 8; ++ks) {
                int r = mt2 * 32 + cl;
                bf16x8 kf = *(const bf16x8*)&Ks[r * 128 + (((2 * ks + h) ^ (r & 7)) << 3)];
                S = __builtin_amdgcn_mfma_f32_32x32x16_bf16(kf, qf[ks], S, 0, 0, 0);
            }
            #pragma unroll
            for (int r2 = 0; r2 < 4; ++r2) {
                float p0 = __builtin_amdgcn_exp2f(S[4 * r2 + 0]);
                float p1 = __builtin_amdgcn_exp2f(S[4 * r2 + 1]);
                float p2 = __builtin_amdgcn_exp2f(S[4 * r2 + 2]);
                float p3 = __builtin_amdgcn_exp2f(S[4 * r2 + 3]);
                lsum += (p0 + p1) + (p2 + p3);
                pk[mt2 * 4 + r2][0] = pk2t(p0, p1);
                pk[mt2 * 4 + r2][1] = pk2t(p2, p3);
            }
        }

        // O += P V ; A-frag assembled via shfl_xor(32) exchange (no LDS)
        #pragma unroll
        for (int ks = 0; ks < 4; ++ks) {
            u32 a0 = pk[2 * ks][0], a1 = pk[2 * ks][1];
            u32 b0 = pk[2 * ks + 1][0], b1 = pk[2 * ks + 1][1];
            bool hb = (h != 0);
            u32 own0 = hb ? b0 : a0, own1 = hb ? b1 : a1;
            u32 xf0 = hb ? a0 : b0, xf1 = hb ? a1 : b1;
            u32 rc0 = (u32)__shfl_xor((int)xf0, 32);
            u32 rc1 = (u32)__shfl_xor((int)xf1, 32);
            BF8 A;
            A.u[0] = hb ? rc0 : own0;
            A.u[1] = hb ? rc1 : own1;
            A.u[2] = hb ? own0 : rc0;
            A.u[3] = hb ? own1 : rc1;
            #pragma unroll
            for (int f = 0; f < 4; ++f) {
                int ir = f * 32 + cl;
                bf16x8 vf = *(const bf16x8*)&Vs[ir * 64 + (((2 * ks + h) ^ (ir & 7)) << 3)];
                O[f] = __builtin_amdgcn_mfma_f32_32x32x16_bf16(A.v, vf, O[f], 0, 0, 0);
            }
        }
    }

    // l totals; cross-half exchange via own-wave LDS (no block barrier needed)
    lsum += __shfl_xor(lsum, 32);
    if (h == 0) lex[w][cl] = lsum;
    __asm__ volatile("s_waitcnt lgkmcnt(0)" ::: "memory");

    float linv[16];
    {
        float* lw = lex[w];
        #pragma unroll
        for (int r2 = 0; r2 < 4; ++r2) {
            f32x4 lv = *(const f32x4*)&lw[8 * r2 + 4 * h];
            #pragma unroll
            for (int e = 0; e < 4; ++e) linv[4 * r2 + e] = 1.f / lv[e];
        }
    }

    u16* aop = (mh == 0) ? ao0 : ao1;
    float* lp = (mh == 0) ? l0 : l1;
    if (h == 0) lp[(size_t)b * N_DIM + qw + cl] = lsum;

    // epilogue staging uses buf0 region (last chunk 31 lives in buf1 — disjoint)
    u16* ep = SM + w * 4096;   // [q32][i128] per wave, 8KB each
    #pragma unroll
    for (int f = 0; f < 4; ++f)
        #pragma unroll
        for (int r2 = 0; r2 < 4; ++r2)
            #pragma unroll
            for (int e = 0; e < 4; ++e) {
                int q = 8 * r2 + 4 * h + e;
                ep[q * 128 + f * 32 + cl] = f2bf(O[f][4 * r2 + e] * linv[4 * r2 + e]);
            }
    __asm__ volatile("s_waitcnt lgkmcnt(0)" ::: "memory");
    #pragma unroll
    for (int it = 0; it < 8; ++it) {
        int id = it * 64 + lane;
        int q = id >> 4, l16 = id & 15;
        f32x4 vv = *(const f32x4*)&ep[q * 128 + l16 * 8];
        *(f32x4*)(aop + ((size_t)(b * N_DIM) + qw + q) * I_DIM + l16 * 8) = vv;
    }
}

// ---- 6: out projection + partial combine + BN stats ----
__global__ __launch_bounds__(256) void oproj_kernel(const u16* __restrict__ ao0,
                                                    const u16* __restrict__ ao1,
                                                    const float* __restrict__ l0,
                                                    const float* __restrict__ l1,
                                                    const u16* __restrict__ owb,
                                                    u16* __restrict__ out2,
                                                    float* __restrict__ bnsum,
                                                    float* __restrict__ bnsumsq) {
    const int bid = blockIdx.x;
    const int b = bid & 7, nt = bid >> 3;
    const int n0 = nt * 64;
    const int t = threadIdx.x, lane = t & 63, w = t >> 6;
    const int cl = lane & 31, h = lane >> 5;

    __shared__ u16 Ep[256 * 72];   // [c][n 72pad]
    __shared__ float lsum[C_DIM], lsq[C_DIM];
    lsum[t] = 0.f; lsq[t] = 0.f;
    __syncthreads();

    const int mt = w & 1;
    const int nn = n0 + mt * 32 + cl;
    float w0, w1;
    {
        float la = l0[(size_t)b * N_DIM + nn], lb = l1[(size_t)b * N_DIM + nn];
        float inv = 1.f / (la + lb);
        w0 = la * inv; w1 = lb * inv;
    }
    bf16x8 afr[8];
    {
        const u16* p0 = ao0 + ((size_t)(b * N_DIM) + nn) * I_DIM + h * 8;
        const u16* p1 = ao1 + ((size_t)(b * N_DIM) + nn) * I_DIM + h * 8;
        #pragma unroll
        for (int ks = 0; ks < 8; ++ks) {
            bf16x8 x0 = *(const bf16x8*)(p0 + ks * 16);
            bf16x8 x1 = *(const bf16x8*)(p1 + ks * 16);
            const u16* u0 = (const u16*)&x0;
            const u16* u1 = (const u16*)&x1;
            float c0 = w0 * bf2f(u0[0]) + w1 * bf2f(u1[0]);
            float c1 = w0 * bf2f(u0[1]) + w1 * bf2f(u1[1]);
            float c2 = w0 * bf2f(u0[2]) + w1 * bf2f(u1[2]);
            float c3 = w0 * bf2f(u0[3]) + w1 * bf2f(u1[3]);
            float c4 = w0 * bf2f(u0[4]) + w1 * bf2f(u1[4]);
            float c5 = w0 * bf2f(u0[5]) + w1 * bf2f(u1[5]);
            float c6 = w0 * bf2f(u0[6]) + w1 * bf2f(u1[6]);
            float c7 = w0 * bf2f(u0[7]) + w1 * bf2f(u1[7]);
            BF8 r;
            r.u[0] = pk2(c0, c1); r.u[1] = pk2(c2, c3);
            r.u[2] = pk2(c4, c5); r.u[3] = pk2(c6, c7);
            afr[ks] = r.v;
        }
    }

    f32x16 D[4] = {};
    #pragma unroll
    for (int ks = 0; ks < 8; ++ks) {
        #pragma unroll
        for (int j = 0; j < 4; ++j) {
            int cr = ((w >> 1) * 4 + j) * 32 + cl;
            bf16x8 bfr = *(const bf16x8*)(owb + (size_t)cr * I_DIM + ks * 16 + h * 8);
            D[j] = __builtin_amdgcn_mfma_f32_32x32x16_bf16(afr[ks], bfr, D[j], 0, 0, 0);
        }
    }

    #pragma unroll
    for (int j = 0; j < 4; ++j) {
        int c = ((w >> 1) * 4 + j) * 32 + cl;
        float s1 = 0.f, s2 = 0.f;
        #pragma unroll
        for (int r2 = 0; r2 < 4; ++r2) {
            float v0 = D[j][4 * r2 + 0], v1 = D[j][4 * r2 + 1];
            float v2 = D[j][4 * r2 + 2], v3 = D[j][4 * r2 + 3];
            s1 += (v0 + v1) + (v2 + v3);
            s2 += (v0 * v0 + v1 * v1) + (v2 * v2 + v3 * v3);
            int nb = mt * 32 + 8 * r2 + 4 * h;
            *(u32*)&Ep[c * 72 + nb] = pk2(v0, v1);
            *(u32*)&Ep[c * 72 + nb + 2] = pk2(v2, v3);
        }
        atomicAdd(&lsum[c], s1);
        atomicAdd(&lsq[c], s2);
    }
    __syncthreads();
    #pragma unroll
    for (int it = 0; it < 8; ++it) {
        int id = it * 256 + t;
        int c = id >> 3, l8 = id & 7;
        f32x4 vv = *(const f32x4*)&Ep[c * 72 + l8 * 8];
        *(f32x4*)(out2 + ((size_t)(b * C_DIM) + c) * N_DIM + n0 + l8 * 8) = vv;
    }
    atomicAdd(&bnsum[t], lsum[t]);
    atomicAdd(&bnsumsq[t], lsq[t]);
}

// ---- 7: BN normalize + SE scale + residual ----
__global__ void final_kernel(const float* __restrict__ x, const u16* __restrict__ out2,
                             const float* __restrict__ bnsum, const float* __restrict__ bnsumsq,
                             const float* __restrict__ gamma, const float* __restrict__ beta,
                             const float* __restrict__ chw, float* __restrict__ out) {
    int idx = blockIdx.x * 256 + threadIdx.x;
    int e = idx * 4;
    int b = e >> 20;
    int c = (e >> 12) & 255;
    float mean = bnsum[c] * (1.f / 32768.f);
    float var = bnsumsq[c] * (1.f / 32768.f) - mean * mean;
    float sc = gamma[c] * rsqrtf(var + 1e-5f);
    float sh = beta[c] - mean * sc;
    float cw = chw[b * C_DIM + c];
    ushort4 o16 = ((const ushort4*)out2)[idx];
    float4 xv = ((const float4*)x)[idx];
    float4 res;
    res.x = xv.x + (bf2f(o16.x) * sc + sh) * cw;
    res.y = xv.y + (bf2f(o16.y) * sc + sh) * cw;
    res.z = xv.z + (bf2f(o16.z) * sc + sh) * cw;
    res.w = xv.w + (bf2f(o16.w) * sc + sh) * cw;
    ((float4*)out)[idx] = res;
}

extern "C" void kernel_launch(void* const* d_in, const int* in_sizes, int n_in,
                              void* d_out, int out_size, void* d_ws, size_t ws_size,
                              hipStream_t stream) {
    const float* x   = (const float*)d_in[0];
    const float* tw  = (const float*)d_in[1];
    const float* pw  = (const float*)d_in[2];
    const float* gw  = (const float*)d_in[3];
    const float* ow  = (const float*)d_in[4];
    const float* gam = (const float*)d_in[5];
    const float* bet = (const float*)d_in[6];
    const float* f1w = (const float*)d_in[7];
    const float* f1b = (const float*)d_in[8];
    const float* f2w = (const float*)d_in[9];
    const float* f2b = (const float*)d_in[10];
    float* out = (float*)d_out;

    char* ws = (char*)d_ws;
    float* bnsum   = (float*)(ws + OFF_BNSUM);
    float* bnsumsq = (float*)(ws + OFF_BNSQ);
    float* pooled  = (float*)(ws + OFF_POOL);
    float* chw     = (float*)(ws + OFF_CHW);
    u16*   w3      = (u16*)(ws + OFF_W3);
    u16*   owb     = (u16*)(ws + OFF_OWB);
    u16*   ao0     = (u16*)(ws + OFF_AO0);
    u16*   ao1     = (u16*)(ws + OFF_AO1);
    u16*   theta   = (u16*)(ws + OFF_THETA);
    u16*   phiT    = (u16*)(ws + OFF_PHIT);
    u16*   gT      = (u16*)(ws + OFF_GT);
    float* l0      = (float*)(ws + OFF_L0);
    float* l1      = (float*)(ws + OFF_L1);
    u16*   out2    = (u16*)(ws + OFF_OUT2);

    prep_kernel<<<384, 256, 0, stream>>>(tw, pw, gw, ow, w3, owb, bnsum, pooled);
    qkv_kernel<<<512, 256, 0, stream>>>(x, w3, theta, phiT, gT, pooled);
    se_kernel<<<B_DIM, 256, 0, stream>>>(pooled, f1w, f1b, f2w, f2b, chw);
    attn_kernel<<<512, 256, 0, stream>>>(theta, phiT, gT, ao0, ao1, l0, l1);
    oproj_kernel<<<512, 256, 0, stream>>>(ao0, ao1, l0, l1, owb, out2, bnsum, bnsumsq);
    final_kernel<<<8192, 256, 0, stream>>>(x, out2, bnsum, bnsumsq, gam, bet, chw, out);
}